// Round 5
// baseline (368.720 us; speedup 1.0000x reference)
//
#include <hip/hip_runtime.h>
#include <math.h>

// out[b,h,p,n] = sum_t exp(Total(b,h) - P[t]) * X[b,t,h,p] * B[b,t,h,n]
// P = inclusive prefix sum of A over t (telescoped chunked scan; verified R1-R4).
// Shapes fixed: b=8, s=4096, h=16, p=n=64.

constexpr int Bn = 8;
constexpr int S  = 4096;
constexpr int H  = 16;
constexpr int SEG  = 128;       // prefix segment length
constexpr int NSEG = S / SEG;   // 32
constexpr int SC  = 16;         // superchunks per pair
constexpr int TPB = S / SC;     // 256 t per block
constexpr int TB  = 16;         // t per LDS stage
constexpr int NST = TPB / TB;   // 16 stages

#define AS1 __attribute__((address_space(1)))
#define AS3 __attribute__((address_space(3)))

static __device__ __forceinline__ void g2lds16(const float* g, float* l) {
  __builtin_amdgcn_global_load_lds((const AS1 unsigned int*)g, (AS3 unsigned int*)l, 16, 0, 0);
}
static __device__ __forceinline__ void g2lds4(const float* g, float* l) {
  __builtin_amdgcn_global_load_lds((const AS1 unsigned int*)g, (AS3 unsigned int*)l, 4, 0, 0);
}

// ---------- K1: per-(bb,seg) local prefix of A + segment sums (coalesced) ----------
__global__ __launch_bounds__(256) void scanA(const float* __restrict__ A,
                                             float* __restrict__ Plb,
                                             float* __restrict__ ss) {
  __shared__ float Al[SEG * 17];   // [t][h] padded
  __shared__ float sp[16][17];
  const int bb = blockIdx.x >> 5, seg = blockIdx.x & 31;
  const int tid = threadIdx.x;
  const float* src = A + ((size_t)bb * S + (size_t)seg * SEG) * H;
  #pragma unroll
  for (int k = 0; k < 2; ++k) {                 // 512 float4, coalesced
    const int f = tid + k * 256;
    const float4 v = ((const float4*)src)[f];
    const int t = f >> 2, h0 = (f & 3) * 4;
    Al[t * 17 + h0 + 0] = v.x; Al[t * 17 + h0 + 1] = v.y;
    Al[t * 17 + h0 + 2] = v.z; Al[t * 17 + h0 + 3] = v.w;
  }
  __syncthreads();
  const int h = tid >> 4, j = tid & 15;         // thread (h, j): t-strip j*8..j*8+8
  float vals[8], run = 0.f;
  #pragma unroll
  for (int k = 0; k < 8; ++k) { run += Al[(j * 8 + k) * 17 + h]; vals[k] = run; }
  sp[h][j] = run;
  __syncthreads();
  float pre = 0.f, tot = 0.f;
  #pragma unroll
  for (int jj = 0; jj < 16; ++jj) { const float x = sp[h][jj]; tot += x; if (jj < j) pre += x; }
  if (j == 0) ss[((size_t)bb * NSEG + seg) * H + h] = tot;
  float* Wp = Plb + ((size_t)(bb * H + h)) * S + seg * SEG + j * 8;
  *(float4*)(Wp)     = make_float4(pre + vals[0], pre + vals[1], pre + vals[2], pre + vals[3]);
  *(float4*)(Wp + 4) = make_float4(pre + vals[4], pre + vals[5], pre + vals[6], pre + vals[7]);
}

// ---------- K2: double-buffered staged outer-product accumulation ----------
// Block = 4 waves per (pair, superchunk). Wave w owns output QUADRANT
// (p-half = w>>1, n-half = w&1): 32x32, i.e. 4x4 per lane -> acc = 16 VGPRs.
// All waves consume all TB staged timesteps. Quadrants are disjoint -> no
// cross-wave reduce; each wave atomicAdds its own 16 values.
// NOTE: acc[8][8] (64 regs) + DMA staging spilled to scratch in R3/R4
// (WRITE_SIZE 797/128 MiB). 16-acc tiles are safely under the spill cliff.
__global__ __launch_bounds__(256) void outer_k(const float* __restrict__ X,
                                               const float* __restrict__ Bm,
                                               const float* __restrict__ Plb,
                                               const float* __restrict__ ss,
                                               float* __restrict__ out) {
  // smem: Xs[2][1024] | Bs[2][1024] | Pl[2][16]   (16.1 KB -> 8 blocks/CU)
  __shared__ float smem[2048 + 2048 + 32];
  float* Xs = smem;
  float* Bs = smem + 2048;
  float* Pl = smem + 4096;

  const int blk = blockIdx.x;
  const int pair = blk >> 4, sc = blk & 15;
  const int bb = pair >> 4, hh = pair & 15;
  const int tid = threadIdx.x, w = tid >> 6, lane = tid & 63;
  const int tstart = sc * TPB;
  const int p0 = (w >> 1) * 32 + (lane >> 3) * 4;   // quadrant + 4-row group
  const int n0 = (w & 1) * 32 + (lane & 7) * 4;     // quadrant + 4-col group

  // wave-register scan of 32 segment sums -> exclusive prefix (lane=seg) + total
  float segv = (lane < NSEG) ? ss[((size_t)bb * NSEG + lane) * H + hh] : 0.f;
  float incl = segv;
  #pragma unroll
  for (int off = 1; off < NSEG; off <<= 1) {
    const float u = __shfl_up(incl, off, 64);
    if (lane >= off) incl += u;
  }
  const float tot = __shfl(incl, NSEG - 1, 64);
  const float pe  = incl - segv;                // exclusive seg prefix (lane<32)

  constexpr size_t RS = (size_t)H * 64;         // 1024 floats per t
  const float* Xb = X  + (((size_t)bb * S + tstart) * H + hh) * 64;
  const float* Bb = Bm + (((size_t)bb * S + tstart) * H + hh) * 64;
  const float* Pb = Plb + (size_t)pair * S + tstart;

  float acc[4][4];
  #pragma unroll
  for (int i = 0; i < 4; ++i)
    #pragma unroll
    for (int j = 0; j < 4; ++j) acc[i][j] = 0.f;

  // stage issue: 8 KB (X 4KB + B 4KB). Wave w issues one 1 KB instr for each
  // of X and B covering t-rows w*4..w*4+3; LDS lands [t][64] contiguous.
  #define ISSUE(s_, buf_) do {                                                  \
    const size_t go = (size_t)((s_) * TB + w * 4 + (lane >> 4)) * RS            \
                      + (size_t)(lane & 15) * 4;                                \
    g2lds16(Xb + go, Xs + (buf_) * 1024 + w * 256);                             \
    g2lds16(Bb + go, Bs + (buf_) * 1024 + w * 256);                             \
    if (w == 0 && lane < TB) g2lds4(Pb + (s_) * TB + lane, Pl + (buf_) * 16);   \
  } while (0)

  ISSUE(0, 0);
  for (int s = 0; s < NST; ++s) {
    __syncthreads();                    // stage s resident (barrier drains vmcnt)
    if (s + 1 < NST) ISSUE(s + 1, (s + 1) & 1);
    const int seg = (tstart + s * TB) >> 7;     // stage lies in one 128-seg
    const float cm = tot - __shfl(pe, seg, 64);
    const float* xb = Xs + (s & 1) * 1024;
    const float* bv = Bs + (s & 1) * 1024;
    const float* pl = Pl + (s & 1) * 16;
    #pragma unroll
    for (int tt = 0; tt < TB; ++tt) {
      const float wgt = __expf(cm - pl[tt]);    // exp(Total - P[t]) <= 1
      const float4 xv = *(const float4*)(xb + tt * 64 + p0);
      const float4 b4 = *(const float4*)(bv + tt * 64 + n0);
      const float bs[4] = {b4.x * wgt, b4.y * wgt, b4.z * wgt, b4.w * wgt};
      const float xs[4] = {xv.x, xv.y, xv.z, xv.w};
      #pragma unroll
      for (int i = 0; i < 4; ++i)
        #pragma unroll
        for (int j = 0; j < 4; ++j)
          acc[i][j] = fmaf(xs[i], bs[j], acc[i][j]);
    }
  }

  // disjoint quadrants: direct atomics, no cross-wave reduce, no extra barrier
  float* op = out + (size_t)pair * 4096;
  #pragma unroll
  for (int i = 0; i < 4; ++i)
    #pragma unroll
    for (int j = 0; j < 4; ++j)
      atomicAdd(&op[(size_t)(p0 + i) * 64 + (n0 + j)], acc[i][j]);
  #undef ISSUE
}

extern "C" void kernel_launch(void* const* d_in, const int* in_sizes, int n_in,
                              void* d_out, int out_size, void* d_ws, size_t ws_size,
                              hipStream_t stream) {
  const float* X = (const float*)d_in[0];   // (b, s, h, p)
  const float* A = (const float*)d_in[1];   // (b, s, h)
  const float* B = (const float*)d_in[2];   // (b, s, h, n)
  float* out = (float*)d_out;               // (b, h, p, n)

  float* Plb = (float*)d_ws;                        // 128*4096 floats = 2 MB
  float* ss  = Plb + (size_t)Bn * H * S;            // 4096 floats

  hipMemsetAsync(d_out, 0, (size_t)out_size * sizeof(float), stream);
  scanA<<<Bn * NSEG, 256, 0, stream>>>(A, Plb, ss);
  outer_k<<<Bn * H * SC, 256, 0, stream>>>(X, B, Plb, ss, out);
}